// Round 14
// baseline (234.057 us; speedup 1.0000x reference)
//
#include <hip/hip_runtime.h>
#include <cstdint>

#define CAP 56          // multiple of 8; Poisson(16): P(any node deg>56) ~ 1e-7
#define NBITS 8
#define BINSZ 256
#define BIN_CAP 5120    // mean 4092 + 16 sigma
#define TILE_E 8192
#define SCANN 512

typedef _Float16 h2 __attribute__((ext_vector_type(2)));
typedef _Float16 h4 __attribute__((ext_vector_type(4)));
typedef _Float16 h8 __attribute__((ext_vector_type(8)));

static __device__ inline h8 pkmax8(h8 a, h8 b) {
#if __has_builtin(__builtin_elementwise_max)
    return __builtin_elementwise_max(a, b);        // 4x v_pk_max_f16
#else
    h8 r;
    #pragma unroll
    for (int i = 0; i < 8; i += 2) {
        h2 aa = { a[i], a[i+1] }, bb = { b[i], b[i+1] }, rr;
        asm("v_pk_max_f16 %0, %1, %2" : "=v"(rr) : "v"(aa), "v"(bb));
        r[i] = rr.x; r[i+1] = rr.y;
    }
    return r;
#endif
}

// ---------------------------------------------------------------------------
// Pass A: bin edges by dst>>8 (391 bins). [R11 config — unchanged]
// ---------------------------------------------------------------------------
__global__ __launch_bounds__(256) void bin_kernel(
    const int* __restrict__ ei, int* __restrict__ bin_cnt,
    int* __restrict__ pairs, int E, int nbins)
{
    __shared__ int hist[SCANN];
    __shared__ int sc[SCANN];
    __shared__ int gbase[SCANN];
    __shared__ int lofs[SCANN];
    __shared__ int words[TILE_E];            // 32KB
    __shared__ unsigned short binOf[TILE_E]; // 16KB
    int t = threadIdx.x;
    for (int i = t; i < SCANN; i += 256) { hist[i] = 0; lofs[i] = 0; }
    __syncthreads();
    int e0 = blockIdx.x * TILE_E;
    int s[32], d[32];
    #pragma unroll
    for (int i = 0; i < 32; ++i) {
        int e = e0 + t + i * 256;
        bool ok = e < E;
        s[i] = ok ? ei[e] : 0;
        d[i] = ok ? ei[E + e] : -1;
        if (ok) atomicAdd(&hist[d[i] >> NBITS], 1);
    }
    __syncthreads();
    sc[t] = hist[t]; sc[t + 256] = hist[t + 256];
    __syncthreads();
    for (int off = 1; off < SCANN; off <<= 1) {
        int i0 = t, i1 = t + 256;
        int v0 = (i0 >= off) ? sc[i0 - off] : 0;
        int v1 = (i1 >= off) ? sc[i1 - off] : 0;
        __syncthreads();
        sc[i0] += v0; sc[i1] += v1;
        __syncthreads();
    }
    for (int i = t; i < nbins; i += 256)
        gbase[i] = atomicAdd(&bin_cnt[i], hist[i]);
    __syncthreads();
    #pragma unroll
    for (int i = 0; i < 32; ++i) {
        if (d[i] >= 0) {
            int b = d[i] >> NBITS;
            int p = atomicAdd(&lofs[b], 1);
            int slot = (sc[b] - hist[b]) + p;
            words[slot] = s[i] | ((d[i] & (BINSZ - 1)) << 17);
            binOf[slot] = (unsigned short)b;
        }
    }
    __syncthreads();
    int total = sc[nbins - 1];
    for (int i = t; i < total; i += 256) {
        int b = binOf[i];
        int off = gbase[b] + (i - (sc[b] - hist[b]));
        if (off < BIN_CAP) pairs[b * BIN_CAP + off] = words[i];
    }
}

// ---------------------------------------------------------------------------
// Pass B: LDS-staged scatter -> compact packed CSR (R13 — unchanged).
// ---------------------------------------------------------------------------
__global__ __launch_bounds__(256) void scatter2_kernel(
    const int* __restrict__ pairs, const int* __restrict__ bin_cnt,
    int2* __restrict__ meta, int* __restrict__ bucket,
    int* __restrict__ gtot, int N)
{
    __shared__ int cur[BINSZ];
    __shared__ int lbuck[BINSZ * CAP];     // 57.3 KB
    __shared__ int sc2[BINSZ];
    __shared__ int sbase;
    int t = threadIdx.x;
    int b = blockIdx.x;
    for (int i = t; i < BINSZ; i += 256) cur[i] = 0;
    __syncthreads();
    int cnt = min(bin_cnt[b], BIN_CAP);
    const int* pp = pairs + b * BIN_CAP;
    for (int i = t; i < cnt; i += 256) {
        int w = pp[i];
        int p = atomicAdd(&cur[w >> 17], 1);
        if (p < CAP) lbuck[(w >> 17) * CAP + p] = w & 0x1FFFF;
    }
    __syncthreads();
    int c  = min(cur[t], CAP);
    int pc = (c + 7) & ~7;
    {
        int s0 = (c > 0) ? lbuck[t * CAP] : 0;
        for (int p = c; p < pc; ++p) lbuck[t * CAP + p] = s0;  // max-neutral dup
        sc2[t] = pc;
    }
    __syncthreads();
    for (int off = 1; off < BINSZ; off <<= 1) {
        int v = (t >= off) ? sc2[t - off] : 0;
        __syncthreads();
        sc2[t] += v;
        __syncthreads();
    }
    if (t == BINSZ - 1) sbase = atomicAdd(gtot, sc2[BINSZ - 1]);
    __syncthreads();
    int start = sbase + sc2[t] - pc;
    int n = b * BINSZ + t;
    if (n < N) meta[n] = make_int2(start, c);
    int4* dst = (int4*)bucket;
    const int4* srcv = (const int4*)(lbuck + t * CAP);
    for (int p = 0; p < (pc >> 2); ++p) dst[(start >> 2) + p] = srcv[p];
}

// ---------------------------------------------------------------------------
// xpack: x rows padded to float4; block 0 zeroes bin_cnt + gtot.
// ---------------------------------------------------------------------------
__global__ __launch_bounds__(256) void xpack_kernel(
    const float* __restrict__ x, float4* __restrict__ xp,
    int* __restrict__ bin_cnt, int* __restrict__ gtot, int N)
{
    int n = blockIdx.x * 256 + threadIdx.x;
    if (n < N) xp[n] = make_float4(x[n*3], x[n*3+1], x[n*3+2], 0.f);
    if (blockIdx.x == 0) {
        bin_cnt[threadIdx.x] = 0;
        bin_cnt[threadIdx.x + 256] = 0;
        if (threadIdx.x == 0) *gtot = 0;
    }
}

// ---------------------------------------------------------------------------
// K2+K3 FUSED. R14 changes (agg1_gemm stuck at 63us across R11-R13):
// (1) edge phase INTERLEAVED across the thread-group's 4 nodes: 16 gathers
//     in flight per round (was 8, one node at a time); clamped re-reads of a
//     row's last quad are max-neutral duplicates -> no masks.
// (2) W2[0:64] staged in LDS (32KB slice == L1 size -> suspected L1 thrash /
//     L2-latency in GEMM phase). LDS total 52KB -> 3 blocks/CU (~= current
//     effective occupancy of 2.75).
// ---------------------------------------------------------------------------
__global__ __launch_bounds__(256) void agg1_gemm_kernel(
    const float4* __restrict__ xp, const int2* __restrict__ meta,
    const int* __restrict__ bucket, const float* __restrict__ W1,
    const float* __restrict__ b1, const float* __restrict__ W2,
    const float* __restrict__ b2, h4* __restrict__ u2h, int N)
{
    __shared__ float h1s[64 * 72];         // swizzled (R12)
    __shared__ float4 W2s[64 * 33];        // k-major, pad 33 to break banks
    int tid = threadIdx.x;
    int n0  = blockIdx.x * 64;
    int sub = tid & 15;
    int ng  = tid >> 4;

    {   // stage W2[0:64] -> LDS (coalesced, 8 float4/thread)
        const float4* W2g = (const float4*)W2;
        for (int i = tid; i < 64 * 32; i += 256)
            W2s[(i >> 5) * 33 + (i & 31)] = W2g[i];
    }

    float4 q0 = ((const float4*)(W1 + 0*64))[sub];
    float4 q1 = ((const float4*)(W1 + 1*64))[sub];
    float4 q2 = ((const float4*)(W1 + 2*64))[sub];
    float4 t0 = ((const float4*)(W1 + 3*64))[sub];
    float4 t1 = ((const float4*)(W1 + 4*64))[sub];
    float4 t2 = ((const float4*)(W1 + 5*64))[sub];
    float4 c0 = make_float4(q0.x+t0.x, q0.y+t0.y, q0.z+t0.z, q0.w+t0.w);
    float4 c1 = make_float4(q1.x+t1.x, q1.y+t1.y, q1.z+t1.z, q1.w+t1.w);
    float4 c2 = make_float4(q2.x+t2.x, q2.y+t2.y, q2.z+t2.z, q2.w+t2.w);
    float4 bb = ((const float4*)b1)[sub];

    // ---- interleaved edge phase: 4 nodes (nl = i*16+ng), 4 edges each/round
    float4 mm[4];
    int cnt[4], pcm[4], pcv[4];
    const int4* br[4];
    #pragma unroll
    for (int i = 0; i < 4; ++i) {
        int n = n0 + i*16 + ng;
        int2 mt = (n < N) ? meta[n] : make_int2(0, 0);
        cnt[i] = mt.y;
        int pc = (mt.y + 7) & ~7;
        pcv[i] = pc;
        pcm[i] = (pc > 4) ? pc - 4 : 0;
        br[i]  = (const int4*)(bucket + (mt.y > 0 ? mt.x : 0));  // safe base
        mm[i]  = make_float4(-3e38f, -3e38f, -3e38f, -3e38f);
    }
    int maxpc = max(max(pcv[0], pcv[1]), max(pcv[2], pcv[3]));
    for (int j0 = 0; j0 < maxpc; j0 += 4) {
        int4 id[4];
        #pragma unroll
        for (int i = 0; i < 4; ++i)
            id[i] = br[i][min(j0, pcm[i]) >> 2];   // clamp: dup re-reads, max-neutral
        float4 xs[16];
        #pragma unroll
        for (int i = 0; i < 4; ++i) {
            xs[i*4+0] = xp[id[i].x]; xs[i*4+1] = xp[id[i].y];
            xs[i*4+2] = xp[id[i].z]; xs[i*4+3] = xp[id[i].w];
        }
        #pragma unroll
        for (int i = 0; i < 4; ++i) {
            #pragma unroll
            for (int u = 0; u < 4; ++u) {
                float4 xv = xs[i*4+u];
                float4 v;
                v.x = fmaf(xv.x, c0.x, fmaf(xv.y, c1.x, xv.z * c2.x));
                v.y = fmaf(xv.x, c0.y, fmaf(xv.y, c1.y, xv.z * c2.y));
                v.z = fmaf(xv.x, c0.z, fmaf(xv.y, c1.z, xv.z * c2.z));
                v.w = fmaf(xv.x, c0.w, fmaf(xv.y, c1.w, xv.z * c2.w));
                mm[i].x = fmaxf(mm[i].x, v.x); mm[i].y = fmaxf(mm[i].y, v.y);
                mm[i].z = fmaxf(mm[i].z, v.z); mm[i].w = fmaxf(mm[i].w, v.w);
            }
        }
    }
    #pragma unroll
    for (int i = 0; i < 4; ++i) {
        int nl = i*16 + ng;
        int n  = n0 + nl;
        float4 xd = (n < N) ? xp[n] : make_float4(0.f, 0.f, 0.f, 0.f);
        int colphys = ((((nl >> 2) + sub) & 15) << 2) | (nl & 3);   // swizzle
        bool ok = cnt[i] > 0;
        h1s[(4*sub+0)*72 + colphys] = ok ? fmaxf(mm[i].x + bb.x - (xd.x*t0.x + xd.y*t1.x + xd.z*t2.x), 0.f) : 0.f;
        h1s[(4*sub+1)*72 + colphys] = ok ? fmaxf(mm[i].y + bb.y - (xd.x*t0.y + xd.y*t1.y + xd.z*t2.y), 0.f) : 0.f;
        h1s[(4*sub+2)*72 + colphys] = ok ? fmaxf(mm[i].z + bb.z - (xd.x*t0.z + xd.y*t1.z + xd.z*t2.z), 0.f) : 0.f;
        h1s[(4*sub+3)*72 + colphys] = ok ? fmaxf(mm[i].w + bb.w - (xd.x*t0.w + xd.y*t1.w + xd.z*t2.w), 0.f) : 0.f;
    }
    __syncthreads();

    // ---- GEMM phase (W2 from LDS now)
    int fi = tid & 31;
    int ni = tid >> 5;
    float acc[8][4];
    #pragma unroll
    for (int r = 0; r < 8; ++r)
        #pragma unroll
        for (int c = 0; c < 4; ++c) acc[r][c] = 0.f;

    #pragma unroll 4
    for (int k = 0; k < 64; ++k) {
        float4 w  = W2s[k*33 + fi];
        int cga = ((2*ni)     + (k >> 2)) & 15;
        int cgb = ((2*ni + 1) + (k >> 2)) & 15;
        float4 a0 = *(const float4*)&h1s[k*72 + cga*4];
        float4 a1 = *(const float4*)&h1s[k*72 + cgb*4];
        float hv[8] = {a0.x,a0.y,a0.z,a0.w,a1.x,a1.y,a1.z,a1.w};
        #pragma unroll
        for (int r = 0; r < 8; ++r) {
            acc[r][0] = fmaf(hv[r], w.x, acc[r][0]);
            acc[r][1] = fmaf(hv[r], w.y, acc[r][1]);
            acc[r][2] = fmaf(hv[r], w.z, acc[r][2]);
            acc[r][3] = fmaf(hv[r], w.w, acc[r][3]);
        }
    }
    const float4* W2v = (const float4*)W2;
    float4 bb2 = ((const float4*)b2)[fi];
    float4 wa = W2v[64*32 + fi], wb = W2v[65*32 + fi], wc = W2v[66*32 + fi];
    #pragma unroll
    for (int r = 0; r < 8; ++r) {
        int n = n0 + ni*8 + r;
        if (n >= N) break;
        float4 xd = xp[n];
        h4 o4;
        o4.x = (_Float16)(acc[r][0] + bb2.x + xd.x*wa.x + xd.y*wb.x + xd.z*wc.x);
        o4.y = (_Float16)(acc[r][1] + bb2.y + xd.x*wa.y + xd.y*wb.y + xd.z*wc.y);
        o4.z = (_Float16)(acc[r][2] + bb2.z + xd.x*wa.z + xd.y*wb.z + xd.z*wc.z);
        o4.w = (_Float16)(acc[r][3] + bb2.w + xd.x*wa.w + xd.y*wb.w + xd.z*wc.w);
        u2h[(size_t)n * 32 + fi] = o4;
    }
}

// ---------------------------------------------------------------------------
// K4: 4 nodes/wave, 16 lanes/node, h8 gathers, int4 index prefetch, meta.
// (unchanged from R13)
// ---------------------------------------------------------------------------
__global__ __launch_bounds__(256) void agg2_head_kernel(
    const float* __restrict__ x, const int2* __restrict__ meta,
    const int* __restrict__ bucket, const float* __restrict__ W2,
    const h8* __restrict__ u2v, const float* __restrict__ Wc,
    const float* __restrict__ bc, float* __restrict__ out, int N)
{
    int gid = blockIdx.x * 256 + threadIdx.x;
    int n   = gid >> 4;
    int sub = threadIdx.x & 15;
    if (n >= N) return;
    int2 mt = meta[n];
    int cnt = mt.y;
    int rounds = (cnt + 7) & ~7;
    const int4* brow4 = (const int4*)(bucket + mt.x);
    const _Float16 NEG = (_Float16)(-60000.0f);
    h8 hm = { NEG, NEG, NEG, NEG, NEG, NEG, NEG, NEG };
    int4 ia = brow4[0], ib = brow4[1];
    for (int j0 = 0; j0 < rounds; j0 += 8) {
        int4 na = brow4[(j0 >> 2) + 2];
        int4 nb = brow4[(j0 >> 2) + 3];
        h8 v0 = u2v[(size_t)ia.x * 16 + sub];
        h8 v1 = u2v[(size_t)ia.y * 16 + sub];
        h8 v2 = u2v[(size_t)ia.z * 16 + sub];
        h8 v3 = u2v[(size_t)ia.w * 16 + sub];
        h8 v4 = u2v[(size_t)ib.x * 16 + sub];
        h8 v5 = u2v[(size_t)ib.y * 16 + sub];
        h8 v6 = u2v[(size_t)ib.z * 16 + sub];
        h8 v7 = u2v[(size_t)ib.w * 16 + sub];
        hm = pkmax8(hm, v0); hm = pkmax8(hm, v1);
        hm = pkmax8(hm, v2); hm = pkmax8(hm, v3);
        hm = pkmax8(hm, v4); hm = pkmax8(hm, v5);
        hm = pkmax8(hm, v6); hm = pkmax8(hm, v7);
        ia = na; ib = nb;
    }
    const float4* W2v = (const float4*)W2;
    float4 wa0 = W2v[64*32 + sub*2], wa1 = W2v[64*32 + sub*2 + 1];
    float4 wb0 = W2v[65*32 + sub*2], wb1 = W2v[65*32 + sub*2 + 1];
    float4 wc0 = W2v[66*32 + sub*2], wc1 = W2v[66*32 + sub*2 + 1];
    float x0 = x[n*3], x1 = x[n*3+1], x2 = x[n*3+2];
    float hh[8];
    hh[0] = (cnt > 0) ? fmaxf((float)hm[0] - (x0*wa0.x + x1*wb0.x + x2*wc0.x), 0.f) : 0.f;
    hh[1] = (cnt > 0) ? fmaxf((float)hm[1] - (x0*wa0.y + x1*wb0.y + x2*wc0.y), 0.f) : 0.f;
    hh[2] = (cnt > 0) ? fmaxf((float)hm[2] - (x0*wa0.z + x1*wb0.z + x2*wc0.z), 0.f) : 0.f;
    hh[3] = (cnt > 0) ? fmaxf((float)hm[3] - (x0*wa0.w + x1*wb0.w + x2*wc0.w), 0.f) : 0.f;
    hh[4] = (cnt > 0) ? fmaxf((float)hm[4] - (x0*wa1.x + x1*wb1.x + x2*wc1.x), 0.f) : 0.f;
    hh[5] = (cnt > 0) ? fmaxf((float)hm[5] - (x0*wa1.y + x1*wb1.y + x2*wc1.y), 0.f) : 0.f;
    hh[6] = (cnt > 0) ? fmaxf((float)hm[6] - (x0*wa1.z + x1*wb1.z + x2*wc1.z), 0.f) : 0.f;
    hh[7] = (cnt > 0) ? fmaxf((float)hm[7] - (x0*wa1.w + x1*wb1.w + x2*wc1.w), 0.f) : 0.f;

    int g = sub * 8;
    float l0 = 0.f, l1 = 0.f, l2 = 0.f, l3 = 0.f, l4 = 0.f;
    #pragma unroll
    for (int k = 0; k < 8; ++k) {
        l0 = fmaf(hh[k], Wc[(g+k)*5+0], l0);
        l1 = fmaf(hh[k], Wc[(g+k)*5+1], l1);
        l2 = fmaf(hh[k], Wc[(g+k)*5+2], l2);
        l3 = fmaf(hh[k], Wc[(g+k)*5+3], l3);
        l4 = fmaf(hh[k], Wc[(g+k)*5+4], l4);
    }
    #pragma unroll
    for (int off = 8; off > 0; off >>= 1) {
        l0 += __shfl_xor(l0, off);
        l1 += __shfl_xor(l1, off);
        l2 += __shfl_xor(l2, off);
        l3 += __shfl_xor(l3, off);
        l4 += __shfl_xor(l4, off);
    }
    l0 += bc[0]; l1 += bc[1]; l2 += bc[2]; l3 += bc[3]; l4 += bc[4];
    float mx  = fmaxf(fmaxf(fmaxf(l0, l1), fmaxf(l2, l3)), l4);
    float s   = expf(l0-mx) + expf(l1-mx) + expf(l2-mx) + expf(l3-mx) + expf(l4-mx);
    float lse = mx + logf(s);
    if (sub < 5) {
        float v = (sub == 0) ? l0 : (sub == 1) ? l1 : (sub == 2) ? l2
                : (sub == 3) ? l3 : l4;
        out[n*5 + sub] = v - lse;
    }
}

extern "C" void kernel_launch(void* const* d_in, const int* in_sizes, int n_in,
                              void* d_out, int out_size, void* d_ws, size_t ws_size,
                              hipStream_t stream)
{
    const float* x  = (const float*)d_in[0];
    const int*   ei = (const int*)d_in[1];
    const float* W1 = (const float*)d_in[2];
    const float* b1 = (const float*)d_in[3];
    const float* W2 = (const float*)d_in[4];
    const float* b2 = (const float*)d_in[5];
    const float* Wc = (const float*)d_in[6];
    const float* bc = (const float*)d_in[7];
    float* out = (float*)d_out;

    int N = in_sizes[0] / 3;   // 100000
    int E = in_sizes[1] / 2;   // 1600000
    int nbins = (N + BINSZ - 1) / BINSZ;   // 391

    // Workspace layout (bytes), total ~46 MB (<=102.4 proven):
    //   [0,          25,600,000)  u2h    (N*128 fp16)
    //   [25,600,000  27,200,000)  xp     (N float4)
    //   [27,200,000  35,207,680)  pairs  (391*5120*4 = 8.0MB)
    //   [35,250,000  44,700,000)  bucket (packed CSR ~9.2MB + slack)
    //   [45,000,000  45,800,000)  meta   (N int2)
    //   [45,900,000  +2KB)        bin_cnt (512 ints)
    //   [45,904,096  +4B)         gtot
    char* ws = (char*)d_ws;
    h4*     u2h     = (h4*)    (ws);
    float4* xp      = (float4*)(ws + 25600000);
    int*    pairs   = (int*)   (ws + 27200000);
    int*    bucket  = (int*)   (ws + 35250000);
    int2*   meta    = (int2*)  (ws + 45000000);
    int*    bin_cnt = (int*)   (ws + 45900000);
    int*    gtot    = (int*)   (ws + 45904096);

    xpack_kernel<<<(N + 255) / 256, 256, 0, stream>>>(x, xp, bin_cnt, gtot, N);
    bin_kernel<<<(E + TILE_E - 1) / TILE_E, 256, 0, stream>>>(
        ei, bin_cnt, pairs, E, nbins);
    scatter2_kernel<<<nbins, 256, 0, stream>>>(pairs, bin_cnt, meta, bucket, gtot, N);

    agg1_gemm_kernel<<<(N + 63) / 64, 256, 0, stream>>>(
        xp, meta, bucket, W1, b1, W2, b2, u2h, N);
    agg2_head_kernel<<<(N * 16 + 255) / 256, 256, 0, stream>>>(
        x, meta, bucket, W2, (const h8*)u2h, Wc, bc, out, N);
}

// Round 15
// 224.712 us; speedup vs baseline: 1.0416x; 1.0416x over previous
//
#include <hip/hip_runtime.h>
#include <cstdint>

#define CAP 56          // multiple of 8; Poisson(16): P(any node deg>56) ~ 1e-7
#define NBITS 8
#define BINSZ 256
#define BIN_CAP 5120    // mean 4092 + 16 sigma
#define TILE_E 8192
#define SCANN 512

typedef _Float16 h2 __attribute__((ext_vector_type(2)));
typedef _Float16 h4 __attribute__((ext_vector_type(4)));
typedef _Float16 h8 __attribute__((ext_vector_type(8)));

static __device__ inline h8 pkmax8(h8 a, h8 b) {
#if __has_builtin(__builtin_elementwise_max)
    return __builtin_elementwise_max(a, b);        // 4x v_pk_max_f16
#else
    h8 r;
    #pragma unroll
    for (int i = 0; i < 8; i += 2) {
        h2 aa = { a[i], a[i+1] }, bb = { b[i], b[i+1] }, rr;
        asm("v_pk_max_f16 %0, %1, %2" : "=v"(rr) : "v"(aa), "v"(bb));
        r[i] = rr.x; r[i+1] = rr.y;
    }
    return r;
#endif
}

// ---------------------------------------------------------------------------
// Pass A (R15): bin edges by dst>>8 + ABSORBED xpack (grid-stride x-pad
// before the histogram phase; hides 2.8MB under the 12.8MB edge stream and
// saves one dispatch). Structure otherwise = R11 (best-known: 224.0us;
// R12's smaller tiles and R13's compact CSR both regressed).
// ---------------------------------------------------------------------------
__global__ __launch_bounds__(256) void bin_kernel(
    const int* __restrict__ ei, const float* __restrict__ x,
    float4* __restrict__ xp, int* __restrict__ bin_cnt,
    int* __restrict__ pairs, int E, int N, int nbins)
{
    __shared__ int hist[SCANN];
    __shared__ int sc[SCANN];
    __shared__ int gbase[SCANN];
    __shared__ int lofs[SCANN];
    __shared__ int words[TILE_E];            // 32KB
    __shared__ unsigned short binOf[TILE_E]; // 16KB
    int t = threadIdx.x;
    // absorbed xpack: coalesced grid-stride over nodes
    for (int i = blockIdx.x * 256 + t; i < N; i += gridDim.x * 256)
        xp[i] = make_float4(x[i*3], x[i*3+1], x[i*3+2], 0.f);

    for (int i = t; i < SCANN; i += 256) { hist[i] = 0; lofs[i] = 0; }
    __syncthreads();
    int e0 = blockIdx.x * TILE_E;
    int s[32], d[32];
    #pragma unroll
    for (int i = 0; i < 32; ++i) {
        int e = e0 + t + i * 256;
        bool ok = e < E;
        s[i] = ok ? ei[e] : 0;
        d[i] = ok ? ei[E + e] : -1;
        if (ok) atomicAdd(&hist[d[i] >> NBITS], 1);
    }
    __syncthreads();
    sc[t] = hist[t]; sc[t + 256] = hist[t + 256];
    __syncthreads();
    for (int off = 1; off < SCANN; off <<= 1) {
        int i0 = t, i1 = t + 256;
        int v0 = (i0 >= off) ? sc[i0 - off] : 0;
        int v1 = (i1 >= off) ? sc[i1 - off] : 0;
        __syncthreads();
        sc[i0] += v0; sc[i1] += v1;
        __syncthreads();
    }
    for (int i = t; i < nbins; i += 256)
        gbase[i] = atomicAdd(&bin_cnt[i], hist[i]);
    __syncthreads();
    #pragma unroll
    for (int i = 0; i < 32; ++i) {
        if (d[i] >= 0) {
            int b = d[i] >> NBITS;
            int p = atomicAdd(&lofs[b], 1);
            int slot = (sc[b] - hist[b]) + p;
            words[slot] = s[i] | ((d[i] & (BINSZ - 1)) << 17);
            binOf[slot] = (unsigned short)b;
        }
    }
    __syncthreads();
    int total = sc[nbins - 1];
    for (int i = t; i < total; i += 256) {
        int b = binOf[i];
        int off = gbase[b] + (i - (sc[b] - hist[b]));
        if (off < BIN_CAP) pairs[b * BIN_CAP + off] = words[i];
    }
}

// ---------------------------------------------------------------------------
// Pass B: LDS-staged scatter, fixed-CAP slice + full int4 streamout (R11 —
// the compact-CSR variant (R13) cost +5us in scan/meta overhead). Writes
// cursor for every node -> no cursor memset needed.
// ---------------------------------------------------------------------------
__global__ __launch_bounds__(256) void scatter2_kernel(
    const int* __restrict__ pairs, const int* __restrict__ bin_cnt,
    int* __restrict__ cursor, int* __restrict__ bucket, int N)
{
    __shared__ int cur[BINSZ];
    __shared__ int lbuck[BINSZ * CAP];     // 57.3 KB
    int t = threadIdx.x;
    int b = blockIdx.x;
    for (int i = t; i < BINSZ; i += 256) cur[i] = 0;
    __syncthreads();
    int cnt = min(bin_cnt[b], BIN_CAP);
    const int* pp = pairs + b * BIN_CAP;
    for (int i = t; i < cnt; i += 256) {
        int w = pp[i];
        int p = atomicAdd(&cur[w >> 17], 1);
        if (p < CAP) lbuck[(w >> 17) * CAP + p] = w & 0x1FFFF;
    }
    __syncthreads();
    int nbase = b * BINSZ;
    for (int dl = t; dl < BINSZ; dl += 256) {
        int n = nbase + dl;
        if (n >= N) continue;
        int c = min(cur[dl], CAP);
        int e = (c + 7) & ~7;
        int s0 = (c > 0) ? lbuck[dl * CAP] : 0;
        for (int p = c; p < e; ++p) lbuck[dl * CAP + p] = s0;  // max-neutral dup
        cursor[n] = c;
    }
    __syncthreads();
    int4* dst = (int4*)(bucket + (size_t)nbase * CAP);
    const int4* srcv = (const int4*)lbuck;
    for (int i = t; i < BINSZ * CAP / 4; i += 256) dst[i] = srcv[i];
}

// ---------------------------------------------------------------------------
// K2+K3 FUSED: layer-1 aggregation by recompute + dense GEMM. R11 structure
// (48 VGPR, sequential 4-pass edge phase with int4 index prefetch) + R12's
// free h1s swizzle (conflicts 3.0M -> 0.2M). R14's interleave + W2-LDS both
// regressed (VGPR 80, occ 24%) — this kernel is at a latency/occupancy
// equilibrium; do not add per-thread state.
// ---------------------------------------------------------------------------
__global__ __launch_bounds__(256) void agg1_gemm_kernel(
    const float4* __restrict__ xp, const int* __restrict__ cursor,
    const int* __restrict__ bucket, const float* __restrict__ W1,
    const float* __restrict__ b1, const float* __restrict__ W2,
    const float* __restrict__ b2, h4* __restrict__ u2h, int N)
{
    __shared__ float h1s[64 * 72];         // swizzled (R12)
    int tid = threadIdx.x;
    int n0  = blockIdx.x * 64;
    int sub = tid & 15;
    int ng  = tid >> 4;

    float4 q0 = ((const float4*)(W1 + 0*64))[sub];
    float4 q1 = ((const float4*)(W1 + 1*64))[sub];
    float4 q2 = ((const float4*)(W1 + 2*64))[sub];
    float4 t0 = ((const float4*)(W1 + 3*64))[sub];
    float4 t1 = ((const float4*)(W1 + 4*64))[sub];
    float4 t2 = ((const float4*)(W1 + 5*64))[sub];
    float4 c0 = make_float4(q0.x+t0.x, q0.y+t0.y, q0.z+t0.z, q0.w+t0.w);
    float4 c1 = make_float4(q1.x+t1.x, q1.y+t1.y, q1.z+t1.z, q1.w+t1.w);
    float4 c2 = make_float4(q2.x+t2.x, q2.y+t2.y, q2.z+t2.z, q2.w+t2.w);
    float4 bb = ((const float4*)b1)[sub];

    #pragma unroll
    for (int pass = 0; pass < 4; ++pass) {
        int nl = pass * 16 + ng;
        int n  = n0 + nl;
        float4 m = make_float4(-3e38f, -3e38f, -3e38f, -3e38f);
        int cnt = 0;
        if (n < N) {
            cnt = cursor[n];
            int rounds = (cnt + 7) & ~7;
            const int4* brow4 = (const int4*)(bucket + (size_t)n * CAP);
            int4 ia = brow4[0], ib = brow4[1];
            for (int j0 = 0; j0 < rounds; j0 += 8) {
                int4 na = brow4[(j0 >> 2) + 2];       // prefetch next round
                int4 nb = brow4[(j0 >> 2) + 3];       // (stays within slice+slack)
                float4 xs[8];
                xs[0] = xp[ia.x]; xs[1] = xp[ia.y]; xs[2] = xp[ia.z]; xs[3] = xp[ia.w];
                xs[4] = xp[ib.x]; xs[5] = xp[ib.y]; xs[6] = xp[ib.z]; xs[7] = xp[ib.w];
                #pragma unroll
                for (int u = 0; u < 8; ++u) {
                    float4 v;
                    v.x = fmaf(xs[u].x, c0.x, fmaf(xs[u].y, c1.x, xs[u].z * c2.x));
                    v.y = fmaf(xs[u].x, c0.y, fmaf(xs[u].y, c1.y, xs[u].z * c2.y));
                    v.z = fmaf(xs[u].x, c0.z, fmaf(xs[u].y, c1.z, xs[u].z * c2.z));
                    v.w = fmaf(xs[u].x, c0.w, fmaf(xs[u].y, c1.w, xs[u].z * c2.w));
                    m.x = fmaxf(m.x, v.x); m.y = fmaxf(m.y, v.y);
                    m.z = fmaxf(m.z, v.z); m.w = fmaxf(m.w, v.w);
                }
                ia = na; ib = nb;
            }
        }
        float4 xd = (n < N) ? xp[n] : make_float4(0.f, 0.f, 0.f, 0.f);
        int colphys = ((((nl >> 2) + sub) & 15) << 2) | (nl & 3);   // swizzle
        h1s[(4*sub+0)*72 + colphys] = (cnt > 0) ? fmaxf(m.x + bb.x - (xd.x*t0.x + xd.y*t1.x + xd.z*t2.x), 0.f) : 0.f;
        h1s[(4*sub+1)*72 + colphys] = (cnt > 0) ? fmaxf(m.y + bb.y - (xd.x*t0.y + xd.y*t1.y + xd.z*t2.y), 0.f) : 0.f;
        h1s[(4*sub+2)*72 + colphys] = (cnt > 0) ? fmaxf(m.z + bb.z - (xd.x*t0.z + xd.y*t1.z + xd.z*t2.z), 0.f) : 0.f;
        h1s[(4*sub+3)*72 + colphys] = (cnt > 0) ? fmaxf(m.w + bb.w - (xd.x*t0.w + xd.y*t1.w + xd.z*t2.w), 0.f) : 0.f;
    }
    __syncthreads();

    int fi = tid & 31;
    int ni = tid >> 5;
    float acc[8][4];
    #pragma unroll
    for (int r = 0; r < 8; ++r)
        #pragma unroll
        for (int c = 0; c < 4; ++c) acc[r][c] = 0.f;

    const float4* W2v = (const float4*)W2;
    #pragma unroll 4
    for (int k = 0; k < 64; ++k) {
        float4 w  = W2v[k*32 + fi];
        int cga = ((2*ni)     + (k >> 2)) & 15;
        int cgb = ((2*ni + 1) + (k >> 2)) & 15;
        float4 a0 = *(const float4*)&h1s[k*72 + cga*4];
        float4 a1 = *(const float4*)&h1s[k*72 + cgb*4];
        float hv[8] = {a0.x,a0.y,a0.z,a0.w,a1.x,a1.y,a1.z,a1.w};
        #pragma unroll
        for (int r = 0; r < 8; ++r) {
            acc[r][0] = fmaf(hv[r], w.x, acc[r][0]);
            acc[r][1] = fmaf(hv[r], w.y, acc[r][1]);
            acc[r][2] = fmaf(hv[r], w.z, acc[r][2]);
            acc[r][3] = fmaf(hv[r], w.w, acc[r][3]);
        }
    }
    float4 bb2 = ((const float4*)b2)[fi];
    float4 wa = W2v[64*32 + fi], wb = W2v[65*32 + fi], wc = W2v[66*32 + fi];
    #pragma unroll
    for (int r = 0; r < 8; ++r) {
        int n = n0 + ni*8 + r;
        if (n >= N) break;
        float4 xd = xp[n];
        h4 o4;
        o4.x = (_Float16)(acc[r][0] + bb2.x + xd.x*wa.x + xd.y*wb.x + xd.z*wc.x);
        o4.y = (_Float16)(acc[r][1] + bb2.y + xd.x*wa.y + xd.y*wb.y + xd.z*wc.y);
        o4.z = (_Float16)(acc[r][2] + bb2.z + xd.x*wa.z + xd.y*wb.z + xd.z*wc.z);
        o4.w = (_Float16)(acc[r][3] + bb2.w + xd.x*wa.w + xd.y*wb.w + xd.z*wc.w);
        u2h[(size_t)n * 32 + fi] = o4;
    }
}

// ---------------------------------------------------------------------------
// K4: 4 nodes/wave, 16 lanes/node, h8 gathers, int4 index prefetch. (R11 —
// the restructure that dropped it out of the top-5.)
// ---------------------------------------------------------------------------
__global__ __launch_bounds__(256) void agg2_head_kernel(
    const float* __restrict__ x, const int* __restrict__ cursor,
    const int* __restrict__ bucket, const float* __restrict__ W2,
    const h8* __restrict__ u2v, const float* __restrict__ Wc,
    const float* __restrict__ bc, float* __restrict__ out, int N)
{
    int gid = blockIdx.x * 256 + threadIdx.x;
    int n   = gid >> 4;
    int sub = threadIdx.x & 15;
    if (n >= N) return;
    int cnt = cursor[n];
    int rounds = (cnt + 7) & ~7;
    const int4* brow4 = (const int4*)(bucket + (size_t)n * CAP);
    const _Float16 NEG = (_Float16)(-60000.0f);
    h8 hm = { NEG, NEG, NEG, NEG, NEG, NEG, NEG, NEG };
    int4 ia = brow4[0], ib = brow4[1];
    for (int j0 = 0; j0 < rounds; j0 += 8) {
        int4 na = brow4[(j0 >> 2) + 2];
        int4 nb = brow4[(j0 >> 2) + 3];
        h8 v0 = u2v[(size_t)ia.x * 16 + sub];
        h8 v1 = u2v[(size_t)ia.y * 16 + sub];
        h8 v2 = u2v[(size_t)ia.z * 16 + sub];
        h8 v3 = u2v[(size_t)ia.w * 16 + sub];
        h8 v4 = u2v[(size_t)ib.x * 16 + sub];
        h8 v5 = u2v[(size_t)ib.y * 16 + sub];
        h8 v6 = u2v[(size_t)ib.z * 16 + sub];
        h8 v7 = u2v[(size_t)ib.w * 16 + sub];
        hm = pkmax8(hm, v0); hm = pkmax8(hm, v1);
        hm = pkmax8(hm, v2); hm = pkmax8(hm, v3);
        hm = pkmax8(hm, v4); hm = pkmax8(hm, v5);
        hm = pkmax8(hm, v6); hm = pkmax8(hm, v7);
        ia = na; ib = nb;
    }
    const float4* W2v = (const float4*)W2;
    float4 wa0 = W2v[64*32 + sub*2], wa1 = W2v[64*32 + sub*2 + 1];
    float4 wb0 = W2v[65*32 + sub*2], wb1 = W2v[65*32 + sub*2 + 1];
    float4 wc0 = W2v[66*32 + sub*2], wc1 = W2v[66*32 + sub*2 + 1];
    float x0 = x[n*3], x1 = x[n*3+1], x2 = x[n*3+2];
    float hh[8];
    hh[0] = (cnt > 0) ? fmaxf((float)hm[0] - (x0*wa0.x + x1*wb0.x + x2*wc0.x), 0.f) : 0.f;
    hh[1] = (cnt > 0) ? fmaxf((float)hm[1] - (x0*wa0.y + x1*wb0.y + x2*wc0.y), 0.f) : 0.f;
    hh[2] = (cnt > 0) ? fmaxf((float)hm[2] - (x0*wa0.z + x1*wb0.z + x2*wc0.z), 0.f) : 0.f;
    hh[3] = (cnt > 0) ? fmaxf((float)hm[3] - (x0*wa0.w + x1*wb0.w + x2*wc0.w), 0.f) : 0.f;
    hh[4] = (cnt > 0) ? fmaxf((float)hm[4] - (x0*wa1.x + x1*wb1.x + x2*wc1.x), 0.f) : 0.f;
    hh[5] = (cnt > 0) ? fmaxf((float)hm[5] - (x0*wa1.y + x1*wb1.y + x2*wc1.y), 0.f) : 0.f;
    hh[6] = (cnt > 0) ? fmaxf((float)hm[6] - (x0*wa1.z + x1*wb1.z + x2*wc1.z), 0.f) : 0.f;
    hh[7] = (cnt > 0) ? fmaxf((float)hm[7] - (x0*wa1.w + x1*wb1.w + x2*wc1.w), 0.f) : 0.f;

    int g = sub * 8;
    float l0 = 0.f, l1 = 0.f, l2 = 0.f, l3 = 0.f, l4 = 0.f;
    #pragma unroll
    for (int k = 0; k < 8; ++k) {
        l0 = fmaf(hh[k], Wc[(g+k)*5+0], l0);
        l1 = fmaf(hh[k], Wc[(g+k)*5+1], l1);
        l2 = fmaf(hh[k], Wc[(g+k)*5+2], l2);
        l3 = fmaf(hh[k], Wc[(g+k)*5+3], l3);
        l4 = fmaf(hh[k], Wc[(g+k)*5+4], l4);
    }
    #pragma unroll
    for (int off = 8; off > 0; off >>= 1) {
        l0 += __shfl_xor(l0, off);
        l1 += __shfl_xor(l1, off);
        l2 += __shfl_xor(l2, off);
        l3 += __shfl_xor(l3, off);
        l4 += __shfl_xor(l4, off);
    }
    l0 += bc[0]; l1 += bc[1]; l2 += bc[2]; l3 += bc[3]; l4 += bc[4];
    float mx  = fmaxf(fmaxf(fmaxf(l0, l1), fmaxf(l2, l3)), l4);
    float s   = expf(l0-mx) + expf(l1-mx) + expf(l2-mx) + expf(l3-mx) + expf(l4-mx);
    float lse = mx + logf(s);
    if (sub < 5) {
        float v = (sub == 0) ? l0 : (sub == 1) ? l1 : (sub == 2) ? l2
                : (sub == 3) ? l3 : l4;
        out[n*5 + sub] = v - lse;
    }
}

extern "C" void kernel_launch(void* const* d_in, const int* in_sizes, int n_in,
                              void* d_out, int out_size, void* d_ws, size_t ws_size,
                              hipStream_t stream)
{
    const float* x  = (const float*)d_in[0];
    const int*   ei = (const int*)d_in[1];
    const float* W1 = (const float*)d_in[2];
    const float* b1 = (const float*)d_in[3];
    const float* W2 = (const float*)d_in[4];
    const float* b2 = (const float*)d_in[5];
    const float* Wc = (const float*)d_in[6];
    const float* bc = (const float*)d_in[7];
    float* out = (float*)d_out;

    int N = in_sizes[0] / 3;   // 100000
    int E = in_sizes[1] / 2;   // 1600000
    int nbins = (N + BINSZ - 1) / BINSZ;   // 391

    // Workspace layout (bytes), total ~58.2 MB (<=102.4 proven):
    //   [0,          25,600,000)  u2h    (N*128 fp16)
    //   [25,600,000  27,200,000)  xp     (N float4)
    //   [27,200,000  35,207,680)  pairs  (391*5120*4 = 8.0MB)
    //   [35,250,000  57,671,504)  bucket (nbins*BINSZ*CAP*4 fixed slices;
    //                                     slack covers idx-prefetch overread)
    //   [57,700,000  58,100,384)  cursor (N*4; written by scatter2, no memset)
    //   [58,200,000  +2KB)        bin_cnt (512 ints)
    char* ws = (char*)d_ws;
    h4*     u2h     = (h4*)    (ws);
    float4* xp      = (float4*)(ws + 25600000);
    int*    pairs   = (int*)   (ws + 27200000);
    int*    bucket  = (int*)   (ws + 35250000);
    int*    cursor  = (int*)   (ws + 57700000);
    int*    bin_cnt = (int*)   (ws + 58200000);

    (void)hipMemsetAsync(bin_cnt, 0, 2048, stream);
    bin_kernel<<<(E + TILE_E - 1) / TILE_E, 256, 0, stream>>>(
        ei, x, xp, bin_cnt, pairs, E, N, nbins);
    scatter2_kernel<<<nbins, 256, 0, stream>>>(pairs, bin_cnt, cursor, bucket, N);

    agg1_gemm_kernel<<<(N + 63) / 64, 256, 0, stream>>>(
        xp, cursor, bucket, W1, b1, W2, b2, u2h, N);
    agg2_head_kernel<<<(N * 16 + 255) / 256, 256, 0, stream>>>(
        x, cursor, bucket, W2, (const h8*)u2h, Wc, bc, out, N);
}